// Round 4
// baseline (161.722 us; speedup 1.0000x reference)
//
#include <hip/hip_runtime.h>

// Problem constants (B,C,H,W)=(2,256,56,56), Cr=64, K=7, G=16, stride=1
#define HW     3136          // 56*56
#define C_IN   256
#define CR     64
#define KKG    784           // 49*16
#define NB     2             // batch
#define NPIX   6272          // NB*HW
#define NT25   25            // p-tiles of 256 over NPIX
#define BN_EPS 1e-5f

// Device-global scratch (fully rewritten every call; no cross-call state)
__device__ float g_P[4 * CR * NPIX];       // K-split conv1 partials [kc][o][p]
__device__ float g_T[CR * NPIX];           // conv1 output (pre-BN) [o][p]
__device__ float g_bs[2 * CR * NT25];      // per-block partial sum/sumsq [2][o][px]
__device__ float g_xg[16 * NPIX * 16];     // x transposed: [d][p][cg] = x[b][16cg+d][hw]
__device__ float g_w2s[16 * 49 * CR];      // w2 regrouped: [s][kk][c] = w2[16kk+s][c]

// ---------------- K1a: conv1 partials (o-tile 8, split-K 4), XCD-swizzled ----------------
// grid (825) 1-D, block 256.  (ROUND-0 VERIFIED CODE -- do not restructure: the split-K
// "extra" 12.8 MB g_P round-trip buys 800 blocks of latency hiding; the 200-block
// full-K fusion (round 2) regressed 124->133 us.)
__global__ __launch_bounds__(256) void k1a_conv1(const float* __restrict__ x,
                                                 const float* __restrict__ w1,
                                                 const float* __restrict__ w2) {
  int bid = blockIdx.x;
  if (bid >= 800) {
    int t = bid - 800;
    int idx = t * 256 + threadIdx.x;
    for (int j = idx; j < 16 * 49 * CR; j += 25 * 256) {
      int s  = j / 3136;                   // 49*64 = 3136 per s
      int r  = j - s * 3136;
      int kk = r >> 6;
      int c  = r & 63;                     // g_w2s[s][kk][c] = w2[(16kk+s)*64 + c]
      g_w2s[j] = w2[(16 * kk + s) * CR + c];
    }
    return;
  }
  int kc     = (bid & 7) >> 1;              // constant per XCD-pair
  int parity = bid & 1;
  int unit   = (bid >> 3) * 2 + parity;     // [0, 200)
  int o0     = (unit & 7) * 8;
  int pt     = unit >> 3;                   // [0, 25)
  int p      = pt * 256 + threadIdx.x;
  if (p >= NPIX) return;
  int b = p / HW;
  int u = p - b * HW;

  const float* xb = x + ((size_t)(b * C_IN + kc * 64)) * HW + u;
  const float* w  = w1 + kc * 64;           // w1[o*256 + kc*64 + c]

  float acc[8];
#pragma unroll
  for (int i = 0; i < 8; ++i) acc[i] = 0.0f;
#pragma unroll 8
  for (int c = 0; c < 64; ++c) {
    float xv = xb[(size_t)c * HW];          // coalesced across lanes, L2-resident slice
#pragma unroll
    for (int i = 0; i < 8; ++i)
      acc[i] += w[(o0 + i) * C_IN + c] * xv;  // wave-uniform -> s_load
  }
  float* pp = g_P + ((size_t)kc * CR + o0) * NPIX + p;
#pragma unroll
  for (int i = 0; i < 8; ++i) pp[(size_t)i * NPIX] = acc[i];
}

// ---------------- kRT: fused (reduce partials -> T + partial stats) | (transpose x) ----
// grid (25, 80), block 256.  (ROUND-0 VERIFIED CODE.)
__global__ __launch_bounds__(256) void kRT(const float* __restrict__ x,
                                           const float* __restrict__ b1) {
  int p = blockIdx.x * 256 + threadIdx.x;
  if (blockIdx.y < 64) {
    int o = blockIdx.y;
    bool valid = (p < NPIX);
    float v = 0.0f;
    if (valid) {
      v = b1[o]
        + g_P[((size_t)0 * CR + o) * NPIX + p]
        + g_P[((size_t)1 * CR + o) * NPIX + p]
        + g_P[((size_t)2 * CR + o) * NPIX + p]
        + g_P[((size_t)3 * CR + o) * NPIX + p];
      g_T[(size_t)o * NPIX + p] = v;
    }
    float s  = valid ? v : 0.0f;
    float s2 = valid ? v * v : 0.0f;
#pragma unroll
    for (int off = 32; off > 0; off >>= 1) {
      s  += __shfl_down(s, off);
      s2 += __shfl_down(s2, off);
    }
    __shared__ float sd[8];
    int lane = threadIdx.x & 63, wid = threadIdx.x >> 6;
    if (lane == 0) { sd[wid] = s; sd[4 + wid] = s2; }
    __syncthreads();
    if (threadIdx.x == 0) {
      g_bs[o * NT25 + blockIdx.x]             = sd[0] + sd[1] + sd[2] + sd[3];
      g_bs[CR * NT25 + o * NT25 + blockIdx.x] = sd[4] + sd[5] + sd[6] + sd[7];
    }
  } else {
    int d = blockIdx.y - 64;
    if (p >= NPIX) return;
    int b  = (p >= HW) ? 1 : 0;
    int hw = p - b * HW;
    const float* xp = x + ((size_t)(b * C_IN + d)) * HW + hw;
    float r[16];
#pragma unroll
    for (int cg = 0; cg < 16; ++cg)
      r[cg] = xp[(size_t)cg * (16 * HW)];
    float4* dst = (float4*)(g_xg + (((size_t)d * NPIX + p) << 4));
    dst[0] = make_float4(r[0], r[1], r[2], r[3]);
    dst[1] = make_float4(r[4], r[5], r[6], r[7]);
    dst[2] = make_float4(r[8], r[9], r[10], r[11]);
    dst[3] = make_float4(r[12], r[13], r[14], r[15]);
  }
}

// ---------------- k45: FUSED conv2 + involution, cg-SPLIT x2 for occupancy --------------
// Round-3 counters: 44.4 us, VALUBusy 18%, Occ 14.5%, HBM 16% -> pure latency-bound at
// 1.16 waves/SIMD. Fix: split the 16-cg involution per thread into TWO cg-halves
// (8 cg = 2x float4 per thread). Waves x2 (3328 -> ~3.3/SIMD); conv2 kv recomputed by
// both halves (VALU floor ~11 us, still << 44) but x_g latency now covered.
// kout stored by ch==0 half only (identical FMA order -> same bits, written once).
// grid (32, 13, 2): s = x&15 (wave-uniform), ch = x>>4, y=u-tile, z=b.
__global__ __launch_bounds__(256) void k45(const float* __restrict__ gamma,
                                           const float* __restrict__ beta,
                                           const float* __restrict__ b2,
                                           float* __restrict__ kout,
                                           float* __restrict__ out) {
  // BN finalize (same math/order as before)
  __shared__ float ssc[CR], ssh[CR];
  if (threadIdx.x < CR) {
    int o = threadIdx.x;
    float S = 0.f, S2 = 0.f;
#pragma unroll
    for (int px = 0; px < NT25; ++px) {
      S  += g_bs[o * NT25 + px];
      S2 += g_bs[CR * NT25 + o * NT25 + px];
    }
    const float invN = 1.0f / (float)NPIX;
    float mean = S * invN;
    float var  = S2 * invN - mean * mean;   // population var matches jnp.var
    float inv  = rsqrtf(var + BN_EPS);
    float sc   = gamma[o] * inv;
    ssc[o] = sc;
    ssh[o] = beta[o] - mean * sc;
  }
  __syncthreads();

  int u = blockIdx.y * 256 + threadIdx.x;     // [0, 3136)
  if (u >= HW) return;                        // after the barrier
  int s  = blockIdx.x & 15;                   // wave-uniform
  int ch = blockIdx.x >> 4;                   // cg-half: 0 -> cg 0..7, 1 -> cg 8..15
  int b  = blockIdx.z;

  // Stage this pixel's BN+ReLU'd conv1 column in registers (coalesced across lanes).
  float t_reg[CR];
  const float* Tb = g_T + (size_t)b * HW + u;
#pragma unroll
  for (int c = 0; c < CR; ++c)
    t_reg[c] = fmaxf(fmaf(Tb[(size_t)c * NPIX], ssc[c], ssh[c]), 0.0f);

  int yrow = u / 56;
  int col  = u - yrow * 56;
  const size_t bHW16 = (size_t)(b * HW) << 4;
  float* kb = kout + (size_t)b * (KKG * HW) + (size_t)s * HW + u;
  const float* wbase = g_w2s + (size_t)s * (49 * CR);  // contiguous [kk][c] for this s
  const int cgoff = ch * 8;                   // float offset into the 16-float x_g line

  float acc[8];
#pragma unroll
  for (int i = 0; i < 8; ++i) acc[i] = 0.0f;

#pragma unroll 7
  for (int kk = 0; kk < 49; ++kk) {
    // ---- conv2 for channel t16 = 16kk+s at pixel u (wave-uniform wide s_loads) ----
    // Same FMA order as round-3 -> kout bits identical; both halves compute, ch==0 stores.
    const float* wrow = wbase + kk * CR;
    float kv0 = 0.f, kv1 = 0.f, kv2 = 0.f, kv3 = 0.f;   // 4-way ILP split
#pragma unroll
    for (int c = 0; c < CR; c += 4) {
      kv0 = fmaf(wrow[c + 0], t_reg[c + 0], kv0);
      kv1 = fmaf(wrow[c + 1], t_reg[c + 1], kv1);
      kv2 = fmaf(wrow[c + 2], t_reg[c + 2], kv2);
      kv3 = fmaf(wrow[c + 3], t_reg[c + 3], kv3);
    }
    int t16 = 16 * kk + s;                   // scalar
    float kv = b2[t16] + ((kv0 + kv1) + (kv2 + kv3));
    if (ch == 0)                             // block-uniform branch
      kb[(size_t)kk * (16 * HW)] = kv;       // kout written exactly once

    // ---- involution tap (this half's 8 cg) ----
    int d   = t16 / 49;                      // scalar (SALU magic-mul)
    int kkp = t16 - d * 49;
    int ki  = kkp / 7;
    int kj  = kkp - ki * 7;
    int yy = yrow + ki - 3, xx = col + kj - 3;
    int off;
    if ((unsigned)yy < 56u && (unsigned)xx < 56u) {
      off = yy * 56 + xx;
    } else {
      off = 0;                               // safe address; kv=0 kills the term
      kv = 0.0f;
    }
    const float* xp = g_xg + (((size_t)d * NPIX + off) << 4) + bHW16 + cgoff;
    float4 x0 = *(const float4*)xp;
    float4 x1 = *(const float4*)(xp + 4);
    acc[0] += kv * x0.x;  acc[1] += kv * x0.y;
    acc[2] += kv * x0.z;  acc[3] += kv * x0.w;
    acc[4] += kv * x1.x;  acc[5] += kv * x1.y;
    acc[6] += kv * x1.z;  acc[7] += kv * x1.w;
  }

  // out channel c = 16*(ch*8+i) + s
  float* ob = out + (size_t)b * (C_IN * HW) + (size_t)(cgoff * 16 + s) * HW + u;
#pragma unroll
  for (int i = 0; i < 8; ++i) ob[(size_t)i * (16 * HW)] = acc[i];
}

extern "C" void kernel_launch(void* const* d_in, const int* in_sizes, int n_in,
                              void* d_out, int out_size, void* d_ws, size_t ws_size,
                              hipStream_t stream) {
  const float* x     = (const float*)d_in[0];
  const float* w1    = (const float*)d_in[1];
  const float* b1    = (const float*)d_in[2];
  const float* gamma = (const float*)d_in[3];
  const float* beta  = (const float*)d_in[4];
  const float* w2    = (const float*)d_in[5];
  const float* b2    = (const float*)d_in[6];

  float* out  = (float*)d_out;                       // (B,256,56,56)
  float* kout = out + (size_t)NB * C_IN * HW;        // (B,784,56,56) raw == (B,49,56,56,16)

  k1a_conv1<<<dim3(825), 256, 0, stream>>>(x, w1, w2);
  kRT<<<dim3(25, 80), 256, 0, stream>>>(x, b1);
  k45<<<dim3(32, 13, NB), 256, 0, stream>>>(gamma, beta, b2, kout, out);
}